// Round 7
// baseline (449.536 us; speedup 1.0000x reference)
//
#include <hip/hip_runtime.h>

#define N_NODES 32000
#define NPG     1000
#define BSZ     32
#define NEDGE   512000
#define H       128
#define NL      3
#define NR      8
#define NSEG    (N_NODES * NR)   // 256000 (dst,rel) segments

typedef __attribute__((ext_vector_type(8))) short short8;
typedef __attribute__((ext_vector_type(4))) float float4v;

__device__ __forceinline__ float bf2f(unsigned short u) {
  union { unsigned int i; float f; } v;
  v.i = ((unsigned int)u) << 16;
  return v.f;
}
__device__ __forceinline__ unsigned short f2bf(float f) {
  union { float f; unsigned int i; } v;
  v.f = f;
  unsigned int x = v.i;
  return (unsigned short)((x + 0x7FFFu + ((x >> 16) & 1u)) >> 16);  // RNE
}

// ---------------- fused prep: cvtX | cvtB | per-(dst,rel) count | graph hist ----------
__global__ __launch_bounds__(256) void k_prep(
    const float* __restrict__ x, const float* __restrict__ W_rel,
    const float* __restrict__ W_self, const int* __restrict__ dst,
    const int* __restrict__ etype, const int* __restrict__ graph_id,
    unsigned short* __restrict__ hb, unsigned short* __restrict__ Bt,
    int* __restrict__ cnt, int* __restrict__ gcount)
{
  const int b = blockIdx.x, t = threadIdx.x;
  if (b < 4000) {                       // x fp32 -> h0 bf16 (4000 blocks)
    const size_t i = ((size_t)b * 256 + t) * 4;
    float4 v = *(const float4*)(x + i);
    ushort4 u = { f2bf(v.x), f2bf(v.y), f2bf(v.z), f2bf(v.w) };
    *(ushort4*)(hb + i) = u;
  } else if (b < 5728) {                // weights -> Bt[l][n=out][k=0..1151] (1728 blocks)
    const int g = (b - 4000) * 256 + t;  // 0..442367
    const int k = g % 1152;
    const int n = (g / 1152) % 128;
    const int l = g / (1152 * 128);
    float v = (k < 1024) ? W_rel[((size_t)l * 1024 + k) * 128 + n]
                         : W_self[((size_t)l * 128 + (k - 1024)) * 128 + n];
    Bt[(size_t)l * (128 * 1152) + (size_t)n * 1152 + k] = f2bf(v);
  } else if (b < 7728) {                // per-(dst,rel) edge counts (2000 blocks)
    const int e = (b - 5728) * 256 + t;
    atomicAdd(&cnt[dst[e] * NR + etype[e]], 1);
  } else {                              // graph histogram (125 blocks)
    __shared__ int hist[BSZ];
    if (t < BSZ) hist[t] = 0;
    __syncthreads();
    const int n = (b - 7728) * 256 + t;
    if (n < N_NODES) atomicAdd(&hist[graph_id[n]], 1);
    __syncthreads();
    if (t < BSZ) { int v = hist[t]; if (v) atomicAdd(&gcount[t], v); }
  }
}

// ---------------- 3-phase exclusive scan over NSEG=256000 bins ----------------
__global__ __launch_bounds__(256) void k_scanA(const int* __restrict__ cnt,
                                               int* __restrict__ bsum) {
  __shared__ int red[256];
  const int t = threadIdx.x;
  int4 v = *(const int4*)(cnt + blockIdx.x * 1024 + t * 4);
  red[t] = v.x + v.y + v.z + v.w;
  __syncthreads();
  for (int off = 128; off > 0; off >>= 1) {
    if (t < off) red[t] += red[t + off];
    __syncthreads();
  }
  if (t == 0) bsum[blockIdx.x] = red[0];
}

__global__ __launch_bounds__(256) void k_scanB(const int* __restrict__ bsum,
                                               int* __restrict__ boff,
                                               int* __restrict__ row_ptr2) {
  __shared__ int v[256];
  const int t = threadIdx.x;  // 250 blocks' sums
  v[t] = (t < 250) ? bsum[t] : 0;
  __syncthreads();
  if (t == 0) {
    int r = 0;
    for (int i = 0; i < 250; ++i) { int c = v[i]; v[i] = r; r += c; }
    row_ptr2[NSEG] = r;   // == NEDGE
  }
  __syncthreads();
  if (t < 250) boff[t] = v[t];
}

__global__ __launch_bounds__(256) void k_scanC(const int* __restrict__ cnt,
                                               const int* __restrict__ boff,
                                               int* __restrict__ row_ptr2,
                                               int* __restrict__ cursor) {
  __shared__ int ts[256];
  const int t = threadIdx.x;
  const int base = blockIdx.x * 1024 + t * 4;
  int4 v = *(const int4*)(cnt + base);
  const int s = v.x + v.y + v.z + v.w;
  ts[t] = s;
  __syncthreads();
  for (int off = 1; off < 256; off <<= 1) {   // inclusive Hillis-Steele
    int val = (t >= off) ? ts[t - off] : 0;
    __syncthreads();
    ts[t] += val;
    __syncthreads();
  }
  int ex = ts[t] - s + boff[blockIdx.x];      // exclusive prefix for this thread
  int4 w = { ex, ex + v.x, ex + v.x + v.y, ex + v.x + v.y + v.z };
  *(int4*)(row_ptr2 + base) = w;
  *(int4*)(cursor + base) = w;
}

// ---------------- fill: edge_dat[p] = src*128 grouped by (dst,rel) ----------------
__global__ void k_fill(const int* __restrict__ src, const int* __restrict__ dst,
                       const int* __restrict__ etype, int* __restrict__ cursor,
                       int* __restrict__ edge_dat) {
  int e = blockIdx.x * blockDim.x + threadIdx.x;
  if (e < NEDGE) {
    int p = atomicAdd(&cursor[dst[e] * NR + etype[e]], 1);
    edge_dat[p] = src[e] << 7;   // element offset into h [N,128]
  }
}

// ---------------- segment-sum: one wave per (dst,rel) segment (avg 2 edges) --------
// agg[seg][c] == agg[n, r*128+c]: exactly the GEMM A-layout.
__global__ __launch_bounds__(256) void k_agg(
    const unsigned short* __restrict__ h, const int* __restrict__ row_ptr2,
    const int* __restrict__ edge_dat, unsigned short* __restrict__ agg)
{
  const int seg = blockIdx.x * 4 + (threadIdx.x >> 6);
  const int lane = threadIdx.x & 63;
  const int c0 = lane * 2;
  const int beg = row_ptr2[seg];
  const int end = row_ptr2[seg + 1];
  float sx = 0.f, sy = 0.f;
  int e = beg;
  for (; e + 4 <= end; e += 4) {       // 4 gathers in flight
    int o0 = edge_dat[e], o1 = edge_dat[e + 1], o2 = edge_dat[e + 2], o3 = edge_dat[e + 3];
    unsigned int u0 = *(const unsigned int*)(h + o0 + c0);
    unsigned int u1 = *(const unsigned int*)(h + o1 + c0);
    unsigned int u2 = *(const unsigned int*)(h + o2 + c0);
    unsigned int u3 = *(const unsigned int*)(h + o3 + c0);
    sx += bf2f((unsigned short)(u0 & 0xffff)) + bf2f((unsigned short)(u1 & 0xffff))
        + bf2f((unsigned short)(u2 & 0xffff)) + bf2f((unsigned short)(u3 & 0xffff));
    sy += bf2f((unsigned short)(u0 >> 16)) + bf2f((unsigned short)(u1 >> 16))
        + bf2f((unsigned short)(u2 >> 16)) + bf2f((unsigned short)(u3 >> 16));
  }
  for (; e < end; ++e) {
    int o = edge_dat[e];
    unsigned int u = *(const unsigned int*)(h + o + c0);
    sx += bf2f((unsigned short)(u & 0xffff));
    sy += bf2f((unsigned short)(u >> 16));
  }
  *(unsigned int*)(agg + (size_t)seg * H + c0) =
      (unsigned int)f2bf(sx) | ((unsigned int)f2bf(sy) << 16);
}

// ---------------- MFMA GEMM: relu([agg|h]_bf16 @ Bt^T) -> h_next bf16 ----------------
// M=32000, K=1152, N=128. 128x128 tile, 4 waves of 64x64. (R5-verified layout.)
__global__ __launch_bounds__(256) void k_gemm_mfma(
    const unsigned short* __restrict__ Aagg,   // [N,1024] bf16
    const unsigned short* __restrict__ Ah,     // [N,128]  bf16
    const unsigned short* __restrict__ Bt,     // [128][1152] bf16
    unsigned short* __restrict__ Hnext)        // [N,128] bf16
{
  __shared__ unsigned short lds_a[128 * 72];   // 144B row stride (16B pad)
  __shared__ unsigned short lds_b[128 * 72];
  const int tid  = threadIdx.x;
  const int wave = tid >> 6, lane = tid & 63;
  const int l15 = lane & 15, quad = lane >> 4;
  const int m0 = blockIdx.x * 128;
  const int mb = (wave & 1) * 64;
  const int nb = (wave >> 1) * 64;

  float4v acc[4][4];
  #pragma unroll
  for (int i = 0; i < 4; ++i)
    #pragma unroll
    for (int j = 0; j < 4; ++j) acc[i][j] = (float4v){0.f, 0.f, 0.f, 0.f};

  for (int kc = 0; kc < 1152; kc += 64) {
    __syncthreads();
    const unsigned short* Ap; int lda, kb;
    if (kc < 1024) { Ap = Aagg; lda = 1024; kb = kc; }
    else           { Ap = Ah;   lda = 128;  kb = kc - 1024; }
    #pragma unroll
    for (int s = 0; s < 4; ++s) {
      int f  = s * 256 + tid;       // 0..1023
      int m  = f >> 3;              // 0..127
      int ko = (f & 7) * 8;         // 0..56
      *(uint4*)(lds_a + m * 72 + ko) = *(const uint4*)(Ap + (size_t)(m0 + m) * lda + kb + ko);
      *(uint4*)(lds_b + m * 72 + ko) = *(const uint4*)(Bt + (size_t)m * 1152 + kc + ko);
    }
    __syncthreads();
    #pragma unroll
    for (int ks = 0; ks < 2; ++ks) {
      const int ko = ks * 32 + quad * 8;
      short8 afr[4], bfr[4];
      #pragma unroll
      for (int i = 0; i < 4; ++i)
        afr[i] = *(const short8*)(lds_a + (mb + i * 16 + l15) * 72 + ko);
      #pragma unroll
      for (int j = 0; j < 4; ++j)
        bfr[j] = *(const short8*)(lds_b + (nb + j * 16 + l15) * 72 + ko);
      #pragma unroll
      for (int i = 0; i < 4; ++i)
        #pragma unroll
        for (int j = 0; j < 4; ++j)
          acc[i][j] = __builtin_amdgcn_mfma_f32_16x16x32_bf16(afr[i], bfr[j], acc[i][j], 0, 0, 0);
    }
  }
  // epilogue: relu -> bf16. D: row=quad*4+r, col=l15.
  #pragma unroll
  for (int i = 0; i < 4; ++i)
    #pragma unroll
    for (int j = 0; j < 4; ++j)
      #pragma unroll
      for (int r = 0; r < 4; ++r) {
        int row = m0 + mb + i * 16 + quad * 4 + r;
        int col = nb + j * 16 + l15;
        Hnext[(size_t)row * H + col] = f2bf(fmaxf(acc[i][j][r], 0.f));
      }
}

// ---------------- per-graph partial mean from bf16 h ----------------
__global__ void k_gmean(const unsigned short* __restrict__ hb, float* __restrict__ gmean)
{
  const int g = blockIdx.x, l = blockIdx.y, c = blockIdx.z, t = threadIdx.x;  // 64
  const unsigned short* base =
      hb + ((size_t)(l + 1) * N_NODES + (size_t)g * NPG + (size_t)c * (NPG / 8)) * H + t * 2;
  float sx = 0.f, sy = 0.f;
  for (int i = 0; i < 125; ++i) {
    unsigned int u = *(const unsigned int*)(base + (size_t)i * H);
    sx += bf2f((unsigned short)(u & 0xffff));
    sy += bf2f((unsigned short)(u >> 16));
  }
  float* gp = gmean + (size_t)g * (NL * H) + l * H + t * 2;
  atomicAdd(gp, sx);
  atomicAdd(gp + 1, sy);
}

// ---------------- readout ----------------
__global__ __launch_bounds__(128) void k_final(
    const unsigned short* __restrict__ hb, const float* __restrict__ gmean,
    const int* __restrict__ gcount,
    const float* __restrict__ rel_tb, const float* __restrict__ Zn,
    const float* __restrict__ projW, const float* __restrict__ projB,
    const float* __restrict__ fcW, const float* __restrict__ fcB,
    const float* __restrict__ repSeq,
    const int* __restrict__ head_ids, const int* __restrict__ tail_ids,
    const int* __restrict__ rel_lab, float* __restrict__ out)
{
  const int b = blockIdx.x;
  const int o = threadIdx.x;   // 128
  __shared__ float gm[384], hf[384], tf[384];
  __shared__ float go[128], ho[128], t_o[128], re[128], rs[128], sv[128];
  __shared__ float lg[128], pr[128], red[128], att[3];

  const int hid = head_ids[b], tlid = tail_ids[b], rl = rel_lab[b];
  const float cinv = 1.f / (float)gcount[b];
  #pragma unroll
  for (int l = 0; l < NL; ++l) {
    gm[l * H + o] = gmean[(size_t)b * (NL * H) + l * H + o] * cinv;
    hf[l * H + o] = bf2f(hb[((size_t)(l + 1) * N_NODES + hid) * H + o]);
    tf[l * H + o] = bf2f(hb[((size_t)(l + 1) * N_NODES + tlid) * H + o]);
  }
  re[o] = rel_tb[rl * H + o];
  rs[o] = repSeq[b * H + o];
  __syncthreads();

  float pb = projB[o];
  float sg = pb, sh = pb, st = pb;
  for (int i = 0; i < NL * H; ++i) {
    float wv = projW[i * H + o];
    sg = fmaf(gm[i], wv, sg);
    sh = fmaf(hf[i], wv, sh);
    st = fmaf(tf[i], wv, st);
  }
  go[o] = (sg > 0.f) ? sg : 0.01f * sg;
  ho[o] = sh;
  t_o[o] = st;
  __syncthreads();

  {
    const int k = o & 63;
    const float* v = (o < 64) ? ho : t_o;
    float s = 0.f;
    for (int i = 0; i < H; ++i) s = fmaf(v[i], Zn[k * H + i], s);
    lg[o] = s;
  }
  __syncthreads();
  if (o < 2) {
    float* l0 = &lg[o * 64];
    float* p0 = &pr[o * 64];
    float mx = l0[0];
    for (int k = 1; k < 64; ++k) mx = fmaxf(mx, l0[k]);
    float sum = 0.f;
    for (int k = 0; k < 64; ++k) { float e = __expf(l0[k] - mx); p0[k] = e; sum += e; }
    float inv = 1.f / sum;
    for (int k = 0; k < 64; ++k) p0[k] *= inv;
  }
  __syncthreads();
  {
    float s1 = 0.f, s2 = 0.f;
    for (int k = 0; k < 64; ++k) {
      float z = Zn[k * H + o];
      s1 = fmaf(pr[k], z, s1);
      s2 = fmaf(pr[64 + k], z, s2);
    }
    s1 = 1.f / (1.f + __expf(-s1));
    s2 = 1.f / (1.f + __expf(-s2));
    sv[o] = s1 * s2;
  }
  __syncthreads();
  if (o == 0) {
    float d0 = 0.f, d1 = 0.f, d2 = 0.f;
    for (int i = 0; i < H; ++i) { d0 += re[i] * go[i]; d1 += re[i] * rs[i]; d2 += re[i] * sv[i]; }
    float mx = fmaxf(d0, fmaxf(d1, d2));
    float e0 = __expf(d0 - mx), e1 = __expf(d1 - mx), e2 = __expf(d2 - mx);
    float inv = 1.f / (e0 + e1 + e2);
    att[0] = e0 * inv; att[1] = e1 * inv; att[2] = e2 * inv;
  }
  __syncthreads();
  float va = att[0] * go[o] + att[1] * rs[o] + att[2] * sv[o];

  float p = 0.f;
  p = fmaf(hf[o],       fcW[o],       p);
  p = fmaf(hf[128 + o], fcW[128 + o], p);
  p = fmaf(hf[256 + o], fcW[256 + o], p);
  p = fmaf(tf[o],       fcW[384 + o], p);
  p = fmaf(tf[128 + o], fcW[512 + o], p);
  p = fmaf(tf[256 + o], fcW[640 + o], p);
  p = fmaf(re[o],       fcW[768 + o], p);
  p = fmaf(va,          fcW[896 + o], p);
  red[o] = p;
  __syncthreads();
  if (o == 0) {
    float s = 0.f;
    for (int i = 0; i < 128; ++i) s += red[i];
    out[b] = s + fcB[0];
  }
}

extern "C" void kernel_launch(void* const* d_in, const int* in_sizes, int n_in,
                              void* d_out, int out_size, void* d_ws, size_t ws_size,
                              hipStream_t stream) {
  const float* x        = (const float*)d_in[0];
  const float* W_rel    = (const float*)d_in[1];
  const float* W_self   = (const float*)d_in[2];
  const float* rel_tb   = (const float*)d_in[3];
  const float* Zn       = (const float*)d_in[4];
  const float* proj_W   = (const float*)d_in[5];
  const float* proj_b   = (const float*)d_in[6];
  const float* fc_W     = (const float*)d_in[7];
  const float* fc_b     = (const float*)d_in[8];
  const float* rep_seq  = (const float*)d_in[9];
  const int* src      = (const int*)d_in[10];
  const int* dst      = (const int*)d_in[11];
  const int* etype    = (const int*)d_in[12];
  const int* graph_id = (const int*)d_in[13];
  const int* head_ids = (const int*)d_in[14];
  const int* tail_ids = (const int*)d_in[15];
  const int* rel_lab  = (const int*)d_in[16];
  float* out = (float*)d_out;

  // workspace carve (~105 MB), all 16B aligned
  char* w = (char*)d_ws;
  unsigned short* agg = (unsigned short*)w; w += (size_t)NSEG * H * 2;                 // 65.5 MB
  unsigned short* hb  = (unsigned short*)w; w += (size_t)(NL + 1) * N_NODES * H * 2;   // 32.8 MB
  unsigned short* Bt  = (unsigned short*)w; w += (size_t)NL * 128 * 1152 * 2;          // 0.88 MB
  int* row_ptr2 = (int*)w;  w += (size_t)(NSEG + 4) * 4;                               // 1.02 MB
  int* edge_dat = (int*)w;  w += (size_t)NEDGE * 4;                                    // 2.05 MB
  int* bsum     = (int*)w;  w += (size_t)256 * 4;
  int* boff     = (int*)w;  w += (size_t)256 * 4;
  // zero region: cursor/cnt | gcount | gmean
  char* z = w;
  int* cursor  = (int*)w;   w += (size_t)NSEG * 4;                                     // 1.02 MB
  int* gcount  = (int*)w;   w += (size_t)32 * 4;
  float* gmean = (float*)w; w += (size_t)BSZ * NL * H * 4;
  size_t zbytes = (size_t)(w - z);

  hipMemsetAsync(z, 0, zbytes, stream);
  k_prep <<<7853, 256, 0, stream>>>(x, W_rel, W_self, dst, etype, graph_id,
                                    hb, Bt, cursor, gcount);
  k_scanA<<<NSEG / 1024, 256, 0, stream>>>(cursor, bsum);
  k_scanB<<<1, 256, 0, stream>>>(bsum, boff, row_ptr2);
  k_scanC<<<NSEG / 1024, 256, 0, stream>>>(cursor, boff, row_ptr2, cursor);
  k_fill <<<NEDGE / 256, 256, 0, stream>>>(src, dst, etype, cursor, edge_dat);

  for (int l = 0; l < NL; ++l) {
    const unsigned short* hp = hb + (size_t)l * N_NODES * H;
    unsigned short* hn = hb + (size_t)(l + 1) * N_NODES * H;
    k_agg <<<NSEG / 4, 256, 0, stream>>>(hp, row_ptr2, edge_dat, agg);
    k_gemm_mfma<<<N_NODES / 128, 256, 0, stream>>>(agg, hp, Bt + (size_t)l * 128 * 1152, hn);
  }
  k_gmean<<<dim3(BSZ, NL, 8), 64, 0, stream>>>(hb, gmean);
  k_final<<<BSZ, H, 0, stream>>>(hb, gmean, gcount, rel_tb, Zn, proj_W, proj_b, fc_W, fc_b,
                                 rep_seq, head_ids, tail_ids, rel_lab, out);
  (void)in_sizes; (void)n_in; (void)out_size; (void)ws_size;
}